// Round 13
// baseline (15.343 us; speedup 1.0000x reference)
//
#include <hip/hip_runtime.h>

constexpr int N = 512;
constexpr int D = 128;
constexpr int A = 2;             // anchors per block
constexpr int NBLK = N / A;      // 256 blocks = 1 per CU
constexpr float MARGIN = 1.0f;
constexpr float EPS_T = 1e-16f;

// Main: 2 anchors/block, 256 blocks, 512 threads.
//  P1: 4 passes, TWO independent rows per thread per pass, 8 lanes/row
//      (full 128-B line coalescing -> 64 MB total L2 traffic, same as R9)
//      with R12's short 4-pass chain (rows are ILP-parallel, not serial).
//      Lane sub = tid&7 reads float4 chunks {sub, sub+8, sub+16, sub+24};
//      per-lane accumulation order + xor(1,2,4) tree bitwise-match R9.
//  P2: all 8 waves ballot-compact both anchors' positive distances
//      (ascending-j preserved -> deterministic).
//  P3: thread's k (= tid) hinges vs both anchors' positives (~32 iters).
//  P4: fixed-tree f64 reduction -> partial[4*blk + {0,1,2}].
// Final: single wave, no LDS, no barrier.
__global__ __launch_bounds__(512) void triplet_main_k(
    const float* __restrict__ emb, const int* __restrict__ labels,
    double* __restrict__ partial)
{
    __shared__ float  drow[A][N];
    __shared__ float  posd[A][128];
    __shared__ int    cnt[A][8];
    __shared__ int    npos_s[A];
    __shared__ double red[24];   // [0..7]=sum, [8..15]=npos, [16..23]=ntrip

    const int i0   = blockIdx.x * A;
    const int tid  = threadIdx.x;
    const int lane = tid & 63;
    const int wid  = tid >> 6;
    const int sub  = tid & 7;    // lane-in-row (8 lanes per row)
    const int grp  = tid >> 3;   // 0..63: row-group

    // anchors -> registers: 4 chunks per anchor (8-lane broadcast loads)
    const float4* ea0 = reinterpret_cast<const float4*>(emb + (size_t)i0 * D);
    const float4* ea1 = reinterpret_cast<const float4*>(emb + (size_t)(i0 + 1) * D);
    float4 A0[4], A1[4];
    #pragma unroll
    for (int c = 0; c < 4; ++c) { A0[c] = ea0[sub + 8 * c]; A1[c] = ea1[sub + 8 * c]; }

    const int lk  = labels[tid];        // this thread's k-label
    const int li0 = labels[i0];         // uniform broadcasts
    const int li1 = labels[i0 + 1];

    // ---- P1: 4 passes, 2 rows/thread/pass, 8 lanes/row ----
    #pragma unroll 2
    for (int p = 0; p < 4; ++p) {
        const int r0 = p * 128 + grp;
        const int r1 = r0 + 64;
        const float4* er0 = reinterpret_cast<const float4*>(emb + (size_t)r0 * D);
        const float4* er1 = reinterpret_cast<const float4*>(emb + (size_t)r1 * D);
        float4 V0[4], V1[4];
        #pragma unroll
        for (int c = 0; c < 4; ++c) { V0[c] = er0[sub + 8 * c]; V1[c] = er1[sub + 8 * c]; }
        float sq00 = 0.f, sq01 = 0.f, sq10 = 0.f, sq11 = 0.f;
        #pragma unroll
        for (int c = 0; c < 4; ++c) {
            float d0 = A0[c].x - V0[c].x, d1 = A0[c].y - V0[c].y;
            float d2 = A0[c].z - V0[c].z, d3 = A0[c].w - V0[c].w;
            sq00 += d0 * d0 + d1 * d1 + d2 * d2 + d3 * d3;
            d0 = A1[c].x - V0[c].x; d1 = A1[c].y - V0[c].y;
            d2 = A1[c].z - V0[c].z; d3 = A1[c].w - V0[c].w;
            sq01 += d0 * d0 + d1 * d1 + d2 * d2 + d3 * d3;
            d0 = A0[c].x - V1[c].x; d1 = A0[c].y - V1[c].y;
            d2 = A0[c].z - V1[c].z; d3 = A0[c].w - V1[c].w;
            sq10 += d0 * d0 + d1 * d1 + d2 * d2 + d3 * d3;
            d0 = A1[c].x - V1[c].x; d1 = A1[c].y - V1[c].y;
            d2 = A1[c].z - V1[c].z; d3 = A1[c].w - V1[c].w;
            sq11 += d0 * d0 + d1 * d1 + d2 * d2 + d3 * d3;
        }
        sq00 += __shfl_xor(sq00, 1); sq01 += __shfl_xor(sq01, 1);
        sq10 += __shfl_xor(sq10, 1); sq11 += __shfl_xor(sq11, 1);
        sq00 += __shfl_xor(sq00, 2); sq01 += __shfl_xor(sq01, 2);
        sq10 += __shfl_xor(sq10, 2); sq11 += __shfl_xor(sq11, 2);
        sq00 += __shfl_xor(sq00, 4); sq01 += __shfl_xor(sq01, 4);
        sq10 += __shfl_xor(sq10, 4); sq11 += __shfl_xor(sq11, 4);
        if (sub == 0) {
            drow[0][r0] = (sq00 > 0.f) ? sqrtf(sq00) : 0.f;   // safe sqrt
            drow[1][r0] = (sq01 > 0.f) ? sqrtf(sq01) : 0.f;
            drow[0][r1] = (sq10 > 0.f) ? sqrtf(sq10) : 0.f;
            drow[1][r1] = (sq11 > 0.f) ? sqrtf(sq11) : 0.f;
        }
    }
    __syncthreads();

    // ---- P2: parallel compaction, all 8 waves (ascending-j order kept) ----
    const int j = tid;
    const bool p0 = (labels[j] == li0) && (j != i0);
    const bool p1 = (labels[j] == li1) && (j != i0 + 1);
    const unsigned long long m0 = __ballot(p0);
    const unsigned long long m1 = __ballot(p1);
    if (lane == 0) { cnt[0][wid] = __popcll(m0); cnt[1][wid] = __popcll(m1); }
    __syncthreads();
    int base0 = 0, base1 = 0;
    #pragma unroll
    for (int w = 0; w < 8; ++w) {
        base0 += (w < wid) ? cnt[0][w] : 0;
        base1 += (w < wid) ? cnt[1][w] : 0;
    }
    const unsigned long long lm = (1ull << lane) - 1ull;
    if (p0) posd[0][base0 + __popcll(m0 & lm)] = drow[0][j];
    if (p1) posd[1][base1 + __popcll(m1 & lm)] = drow[1][j];
    if (tid == 0) {
        int t0 = 0, t1 = 0;
        #pragma unroll
        for (int w = 0; w < 8; ++w) { t0 += cnt[0][w]; t1 += cnt[1][w]; }
        npos_s[0] = t0; npos_s[1] = t1;
    }
    __syncthreads();

    // ---- P3: hinge accumulation, k = tid, both anchors ----
    double sum = 0.0;
    int np_i = 0, nt_i = 0;
    {
        const float dik = drow[0][tid];
        if (lk != li0) {
            const int npos = npos_s[0];
            for (int p = 0; p < npos; ++p) {
                const float t = (posd[0][p] - dik) + MARGIN;  // reference op order
                if (t > EPS_T) { sum += (double)t; ++np_i; }
            }
            nt_i += npos;
        }
    }
    {
        const float dik = drow[1][tid];
        if (lk != li1) {
            const int npos = npos_s[1];
            for (int p = 0; p < npos; ++p) {
                const float t = (posd[1][p] - dik) + MARGIN;
                if (t > EPS_T) { sum += (double)t; ++np_i; }
            }
            nt_i += npos;
        }
    }

    // ---- P4: fixed-tree reduction ----
    double s = sum, p = (double)np_i, t = (double)nt_i;
    #pragma unroll
    for (int off = 32; off > 0; off >>= 1) {
        s += __shfl_down(s, off);
        p += __shfl_down(p, off);
        t += __shfl_down(t, off);
    }
    if (lane == 0) { red[wid] = s; red[8 + wid] = p; red[16 + wid] = t; }
    __syncthreads();
    if (tid == 0) {
        double S = 0.0, P = 0.0, T = 0.0;
        #pragma unroll
        for (int w = 0; w < 8; ++w) { S += red[w]; P += red[8 + w]; T += red[16 + w]; }
        partial[4 * blockIdx.x + 0] = S;
        partial[4 * blockIdx.x + 1] = P;
        partial[4 * blockIdx.x + 2] = T;
    }
}

// Single-wave finalizer: no LDS, no barrier.
__global__ __launch_bounds__(64) void triplet_final_k(
    const double* __restrict__ partial, float* __restrict__ out)
{
    const int lane = threadIdx.x;
    double a = 0.0, b = 0.0, c = 0.0;
    #pragma unroll
    for (int bk = lane; bk < NBLK; bk += 64) {
        a += partial[4 * bk + 0];
        b += partial[4 * bk + 1];
        c += partial[4 * bk + 2];
    }
    #pragma unroll
    for (int off = 32; off > 0; off >>= 1) {
        a += __shfl_down(a, off);
        b += __shfl_down(b, off);
        c += __shfl_down(c, off);
    }
    if (lane == 0) {
        out[0] = (float)(a / (b + 1e-16));  // loss
        out[1] = (float)(b / (c + 1e-16));  // fraction_positive
    }
}

extern "C" void kernel_launch(void* const* d_in, const int* in_sizes, int n_in,
                              void* d_out, int out_size, void* d_ws, size_t ws_size,
                              hipStream_t stream) {
    const float* emb   = (const float*)d_in[0];   // [512,128] f32
    const int*   lab   = (const int*)d_in[1];     // [512] i32
    float*       out   = (float*)d_out;           // [2] f32: loss, fraction_positive
    double*      parts = (double*)d_ws;           // 4*NBLK doubles = 8 KB

    triplet_main_k<<<NBLK, 512, 0, stream>>>(emb, lab, parts);
    triplet_final_k<<<1, 64, 0, stream>>>(parts, out);
}